// Round 5
// baseline (502.789 us; speedup 1.0000x reference)
//
#include <hip/hip_runtime.h>
#include <hip/hip_bf16.h>

#define NN 50000
#define NE 800000
#define DD 256
#define OO 32

typedef __attribute__((ext_vector_type(8))) short short8;
typedef __attribute__((ext_vector_type(4))) float float4v;

#define AS1 __attribute__((address_space(1)))
#define AS3 __attribute__((address_space(3)))

__device__ __forceinline__ float lo16f(unsigned int u) {
    union { unsigned int i; float f; } x; x.i = u << 16; return x.f;
}
__device__ __forceinline__ float hi16f(unsigned int u) {
    union { unsigned int i; float f; } x; x.i = u & 0xFFFF0000u; return x.f;
}
__device__ __forceinline__ unsigned short f2b(float f) {
    union { float f; unsigned int i; } x;
    x.f = f;
    unsigned int r = x.i + 0x7FFFu + ((x.i >> 16) & 1u);  // RNE
    return (unsigned short)(r >> 16);
}

// ---------------------------------------------------------------------------
// CSR build
// ---------------------------------------------------------------------------
__global__ void count_kernel(const int* __restrict__ row, int* __restrict__ cnt, int E) {
    int e = blockIdx.x * blockDim.x + threadIdx.x;
    if (e < E) atomicAdd(&cnt[row[e]], 1);
}

__global__ __launch_bounds__(256) void block_sums(const int* __restrict__ cnt,
                                                  int* __restrict__ bsum, int N) {
    __shared__ int s[256];
    int idx = blockIdx.x * 256 + threadIdx.x;
    s[threadIdx.x] = (idx < N) ? cnt[idx] : 0;
    __syncthreads();
    for (int o = 128; o > 0; o >>= 1) {
        if (threadIdx.x < o) s[threadIdx.x] += s[threadIdx.x + o];
        __syncthreads();
    }
    if (threadIdx.x == 0) bsum[blockIdx.x] = s[0];
}

__global__ __launch_bounds__(256) void scan_bsums(const int* __restrict__ bsum,
                                                  int* __restrict__ bpre, int nb) {
    __shared__ int s[256];
    int t = threadIdx.x;
    int v0 = (t < nb) ? bsum[t] : 0;
    s[t] = v0;
    __syncthreads();
    for (int o = 1; o < 256; o <<= 1) {
        int v = (t >= o) ? s[t - o] : 0;
        __syncthreads();
        s[t] += v;
        __syncthreads();
    }
    if (t < nb) bpre[t] = s[t] - v0;  // exclusive prefix
}

__global__ __launch_bounds__(256) void fill_rowptr(const int* __restrict__ cnt,
                                                   const int* __restrict__ bpre,
                                                   int* __restrict__ row_ptr,
                                                   int* __restrict__ cursor,
                                                   float* __restrict__ dinv, int N, int E) {
    __shared__ int s[256];
    int t = threadIdx.x;
    int idx = blockIdx.x * 256 + t;
    int c = (idx < N) ? cnt[idx] : 0;
    s[t] = c;
    __syncthreads();
    for (int o = 1; o < 256; o <<= 1) {
        int v = (t >= o) ? s[t - o] : 0;
        __syncthreads();
        s[t] += v;
        __syncthreads();
    }
    int excl = bpre[blockIdx.x] + s[t] - c;
    if (idx < N) {
        row_ptr[idx] = excl;
        cursor[idx] = excl;
        dinv[idx] = rsqrtf((float)(c + 1));  // +1 self-loop
    }
    if (idx == N) row_ptr[N] = E;
}

__global__ void scatter_kernel(const int* __restrict__ row, const int* __restrict__ col,
                               int* __restrict__ cursor, int* __restrict__ csr_col, int E) {
    int e = blockIdx.x * blockDim.x + threadIdx.x;
    if (e < E) {
        int p = atomicAdd(&cursor[row[e]], 1);
        csr_col[p] = col[e];
    }
}

// ---------------------------------------------------------------------------
// Casts and weight composition
// ---------------------------------------------------------------------------
__global__ __launch_bounds__(256) void cast_x_kernel(const float* __restrict__ x,
                                                     unsigned short* __restrict__ xb, int n4) {
    int i = blockIdx.x * 256 + threadIdx.x;
    if (i < n4) {
        float4 v = ((const float4*)x)[i];
        ushort4 o;
        o.x = f2b(v.x); o.y = f2b(v.y); o.z = f2b(v.z); o.w = f2b(v.w);
        ((ushort4*)xb)[i] = o;
    }
}

// Wt[n][k] = bf16(W[k][n]); y=0: W0, y=1: W1, y=2: W2 (32 cols only)
__global__ __launch_bounds__(256) void cast_wt3_kernel(const float* __restrict__ Wa,
                                                       const float* __restrict__ Wb,
                                                       const float* __restrict__ Wc,
                                                       unsigned short* __restrict__ Ta,
                                                       unsigned short* __restrict__ Tb,
                                                       unsigned short* __restrict__ Tc) {
    int n = blockIdx.x, k = threadIdx.x;
    if (blockIdx.y == 0) Ta[n * 256 + k] = f2b(Wa[k * 256 + n]);
    else if (blockIdx.y == 1) Tb[n * 256 + k] = f2b(Wb[k * 256 + n]);
    else if (n < 32) Tc[n * 256 + k] = f2b(Wc[k * 32 + n]);
}

// WcT[n][k] = bf16( sum_m W[k][m] * Wn[m][n] )  — block = k, thread = n.
__global__ __launch_bounds__(256) void compose_wc(const float* __restrict__ W0,
                                                  const float* __restrict__ Wn0,
                                                  const float* __restrict__ W1,
                                                  const float* __restrict__ Wn1,
                                                  unsigned short* __restrict__ T0,
                                                  unsigned short* __restrict__ T1) {
    const float* W  = blockIdx.y ? W1 : W0;
    const float* Wn = blockIdx.y ? Wn1 : Wn0;
    unsigned short* T = blockIdx.y ? T1 : T0;
    __shared__ float wrow[256];
    int k = blockIdx.x, n = threadIdx.x;
    wrow[n] = W[k * 256 + n];
    __syncthreads();
    float s = 0.f;
#pragma unroll 8
    for (int m = 0; m < 256; ++m) s = fmaf(wrow[m], Wn[m * 256 + n], s);
    T[n * 256 + k] = f2b(s);
}

// bc[n] = sum_m b[m]*Wn[m][n] + bn[n]  (fp32)
__global__ __launch_bounds__(256) void compose_bc(const float* __restrict__ b0_,
                                                  const float* __restrict__ Wn0,
                                                  const float* __restrict__ bn0,
                                                  const float* __restrict__ b1_,
                                                  const float* __restrict__ Wn1,
                                                  const float* __restrict__ bn1,
                                                  float* __restrict__ bc0,
                                                  float* __restrict__ bc1) {
    const float* b  = blockIdx.y ? b1_ : b0_;
    const float* Wn = blockIdx.y ? Wn1 : Wn0;
    const float* bn = blockIdx.y ? bn1 : bn0;
    float* bc = blockIdx.y ? bc1 : bc0;
    int n = threadIdx.x;
    float s = bn[n];
    for (int m = 0; m < 256; ++m) s = fmaf(b[m], Wn[m * 256 + n], s);
    bc[n] = s;
}

// ---------------------------------------------------------------------------
// Persistent-weight dual GEMM.
//   CH = A @ WtH^T + biasH ; CC = A @ WtC^T + biasC   (both [M x 256] bf16)
// Block owns a 64-col quarter of BOTH weight matrices in 64 KB LDS (loaded
// once), then streams 128-row A tiles with NO barriers: A fragments are
// loaded 16B/lane directly global->VGPR (K fully unrolled -> loads pipeline),
// weights via ds_read_b128 with XOR swizzle to kill the stride-64B conflicts.
// Grid (128, 4) = 512 blocks, 2 blocks/CU (LDS-limited).
// ---------------------------------------------------------------------------
__global__ __launch_bounds__(256, 2) void dual_gemm_persist(
    const unsigned short* __restrict__ A,
    const unsigned short* __restrict__ WtH,
    const unsigned short* __restrict__ WtC,
    const float* __restrict__ biasH,
    const float* __restrict__ biasC,
    unsigned short* __restrict__ CH,
    unsigned short* __restrict__ CC,
    int M, int nTiles) {
    __shared__ unsigned short Wls[2][8][64][32];  // [mat][kk][n][k-in-32] = 64 KB
    int tid = threadIdx.x, lane = tid & 63, wave = tid >> 6;
    int colBase = blockIdx.y * 64;

    // Stage weight quarter once. Chunk = 8 ushorts (16B). part' = part ^ ((n>>1)&3)
    for (int ch = tid; ch < 4096; ch += 256) {
        int part = ch & 3;
        int n = (ch >> 2) & 63;
        int kk = (ch >> 8) & 7;
        int mat = ch >> 11;
        const unsigned short* src = mat ? WtC : WtH;
        int partS = part ^ ((n >> 1) & 3);
        *(short8*)&Wls[mat][kk][n][partS * 8] =
            *(const short8*)&src[(size_t)(colBase + n) * 256 + kk * 32 + part * 8];
    }
    __syncthreads();

    int fr = lane & 15;
    int fk = (lane >> 4) * 8;                          // A frag k-offset (unswizzled)
    int fkS = 8 * ((lane >> 4) ^ ((fr >> 1) & 3));     // swizzled LDS k-offset
    int cr = (lane >> 4) * 4;

    float bH[4], bC[4];
#pragma unroll
    for (int j = 0; j < 4; ++j) {
        bH[j] = biasH[colBase + j * 16 + fr];
        bC[j] = biasC[colBase + j * 16 + fr];
    }

    for (int tile = blockIdx.x; tile < nTiles; tile += gridDim.x) {
        int rowBase = tile * 128 + wave * 32;
        float4v accH[2][4], accC[2][4];
#pragma unroll
        for (int i = 0; i < 2; ++i)
#pragma unroll
            for (int j = 0; j < 4; ++j) {
                accH[i][j] = (float4v){0.f, 0.f, 0.f, 0.f};
                accC[i][j] = (float4v){0.f, 0.f, 0.f, 0.f};
            }

        int r0 = rowBase + fr;      if (r0 >= M) r0 = M - 1;
        int r1 = rowBase + 16 + fr; if (r1 >= M) r1 = M - 1;
        const unsigned short* a0p = A + (size_t)r0 * 256 + fk;
        const unsigned short* a1p = A + (size_t)r1 * 256 + fk;

#pragma unroll
        for (int kk = 0; kk < 8; ++kk) {
            short8 a0 = *(const short8*)(a0p + kk * 32);
            short8 a1 = *(const short8*)(a1p + kk * 32);
#pragma unroll
            for (int j = 0; j < 4; ++j) {
                short8 bh = *(const short8*)&Wls[0][kk][j * 16 + fr][fkS];
                short8 bc = *(const short8*)&Wls[1][kk][j * 16 + fr][fkS];
                accH[0][j] = __builtin_amdgcn_mfma_f32_16x16x32_bf16(a0, bh, accH[0][j], 0, 0, 0);
                accH[1][j] = __builtin_amdgcn_mfma_f32_16x16x32_bf16(a1, bh, accH[1][j], 0, 0, 0);
                accC[0][j] = __builtin_amdgcn_mfma_f32_16x16x32_bf16(a0, bc, accC[0][j], 0, 0, 0);
                accC[1][j] = __builtin_amdgcn_mfma_f32_16x16x32_bf16(a1, bc, accC[1][j], 0, 0, 0);
            }
        }

        // Epilogue: direct stores. Per instr: 16-lane runs of 32B (4 rows).
#pragma unroll
        for (int i = 0; i < 2; ++i) {
#pragma unroll
            for (int j = 0; j < 4; ++j) {
#pragma unroll
                for (int r = 0; r < 4; ++r) {
                    int rowg = rowBase + i * 16 + cr + r;
                    if (rowg < M) {
                        size_t off = (size_t)rowg * 256 + colBase + j * 16 + fr;
                        CH[off] = f2b(accH[i][j][r] + bH[j]);
                        CC[off] = f2b(accC[i][j][r] + bC[j]);
                    }
                }
            }
        }
    }
}

// ---------------------------------------------------------------------------
// Fused APPNP agg + residual + L2-norm + ReLU. One WAVE per node.
// Lane half h gathers neighbor 2j+h's row: 16B/lane, 1KB (2 rows) per load
// instr. Partials combined with shfl_xor(32) at the end.
// ---------------------------------------------------------------------------
__global__ __launch_bounds__(256) void agg_norm_relu(const unsigned short* __restrict__ h0,
                                                     const unsigned short* __restrict__ nb,
                                                     const float* __restrict__ dinv,
                                                     const int* __restrict__ row_ptr,
                                                     const int* __restrict__ csr_col,
                                                     unsigned short* __restrict__ outp) {
    int wave = threadIdx.x >> 6, lane = threadIdx.x & 63;
    int half = lane >> 5, s = lane & 31;
    int v = blockIdx.x * 4 + wave;
    float dv = dinv[v];
    const uint4* nb4 = (const uint4*)nb;

    float a0 = 0.f, a1 = 0.f, a2 = 0.f, a3 = 0.f;
    float a4 = 0.f, a5 = 0.f, a6 = 0.f, a7 = 0.f;

    int st = row_ptr[v], en = row_ptr[v + 1];
    for (int b0 = st; b0 < en; b0 += 64) {
        int mm = en - b0;
        if (mm > 64) mm = 64;
        int c = 0;
        float dc = 0.f;
        if (lane < mm) { c = csr_col[b0 + lane]; dc = dinv[c]; }
        int pairs4 = (((mm + 1) >> 1) + 3) & ~3;  // pairs, unrolled by 4
        for (int j = 0; j < pairs4; j += 4) {
            int ci[4];
            float di[4];
            uint4 u[4];
#pragma unroll
            for (int q = 0; q < 4; ++q) {
                int srcl = 2 * (j + q) + half;  // <= 63; lanes >= mm carry c=0,dc=0
                ci[q] = __shfl(c, srcl);
                di[q] = __shfl(dc, srcl);
            }
#pragma unroll
            for (int q = 0; q < 4; ++q) u[q] = nb4[(size_t)ci[q] * 32 + s];
#pragma unroll
            for (int q = 0; q < 4; ++q) {
                a0 = fmaf(di[q], lo16f(u[q].x), a0);
                a1 = fmaf(di[q], hi16f(u[q].x), a1);
                a2 = fmaf(di[q], lo16f(u[q].y), a2);
                a3 = fmaf(di[q], hi16f(u[q].y), a3);
                a4 = fmaf(di[q], lo16f(u[q].z), a4);
                a5 = fmaf(di[q], hi16f(u[q].z), a5);
                a6 = fmaf(di[q], lo16f(u[q].w), a6);
                a7 = fmaf(di[q], hi16f(u[q].w), a7);
            }
        }
    }
    // Combine the two half-partials (feature slot s lives in lanes s and s+32)
    a0 += __shfl_xor(a0, 32); a1 += __shfl_xor(a1, 32);
    a2 += __shfl_xor(a2, 32); a3 += __shfl_xor(a3, 32);
    a4 += __shfl_xor(a4, 32); a5 += __shfl_xor(a5, 32);
    a6 += __shfl_xor(a6, 32); a7 += __shfl_xor(a7, 32);

    if (half == 0) {
        uint4 nbu = nb4[(size_t)v * 32 + s];
        uint4 hu = ((const uint4*)h0)[(size_t)v * 32 + s];
        float nv[8] = {lo16f(nbu.x), hi16f(nbu.x), lo16f(nbu.y), hi16f(nbu.y),
                       lo16f(nbu.z), hi16f(nbu.z), lo16f(nbu.w), hi16f(nbu.w)};
        float hv[8] = {lo16f(hu.x), hi16f(hu.x), lo16f(hu.y), hi16f(hu.y),
                       lo16f(hu.z), hi16f(hu.z), lo16f(hu.w), hi16f(hu.w)};
        float aa[8] = {a0, a1, a2, a3, a4, a5, a6, a7};
        float vv[8];
        float ss = 0.f;
#pragma unroll
        for (int i = 0; i < 8; ++i) {
            vv[i] = hv[i] + 0.5f * dv * (dv * nv[i] + aa[i]) + 0.5f * nv[i];
            ss = fmaf(vv[i], vv[i], ss);
        }
#pragma unroll
        for (int o = 16; o > 0; o >>= 1) ss += __shfl_xor(ss, o, 32);
        float inv = 1.0f / fmaxf(sqrtf(ss), 1e-12f);
        unsigned short ov[8];
#pragma unroll
        for (int i = 0; i < 8; ++i) ov[i] = f2b(fmaxf(vv[i] * inv, 0.f));
        *(short8*)&outp[(size_t)v * 256 + s * 8] = *(short8*)ov;
    }
}

// ---------------------------------------------------------------------------
// Final projection (MFMA): out[M x 32](fp32) = A[M x 256](bf16) @ W2 + b2
// ---------------------------------------------------------------------------
__global__ __launch_bounds__(256) void gemm_final_mfma(const unsigned short* __restrict__ A,
                                                       const unsigned short* __restrict__ Wt2,
                                                       const float* __restrict__ b2,
                                                       float* __restrict__ out, int M) {
    __shared__ unsigned short Als[128 * 32];
    __shared__ unsigned short Bls[32 * 32];
    int tid = threadIdx.x;
    int lane = tid & 63, wave = tid >> 6;
    int rowBase = blockIdx.x * 128;

    float4v acc[2][2];
#pragma unroll
    for (int i = 0; i < 2; ++i)
#pragma unroll
        for (int j = 0; j < 2; ++j) acc[i][j] = (float4v){0.f, 0.f, 0.f, 0.f};

    int sRow = wave * 32 + (lane >> 2);
    int sK = (lane & 3) * 8;
    int fr = lane & 15, fk = (lane >> 4) * 8;
    int bn = tid >> 3, bk4 = (tid & 7) * 4;

    for (int k0 = 0; k0 < 256; k0 += 32) {
        int r0 = rowBase + sRow;       if (r0 >= M) r0 = M - 1;
        int r1 = rowBase + sRow + 16;  if (r1 >= M) r1 = M - 1;
        __builtin_amdgcn_global_load_lds((const AS1 void*)(A + (size_t)r0 * 256 + k0 + sK),
                                         (AS3 void*)&Als[(wave * 32) * 32], 16, 0, 0);
        __builtin_amdgcn_global_load_lds((const AS1 void*)(A + (size_t)r1 * 256 + k0 + sK),
                                         (AS3 void*)&Als[(wave * 32 + 16) * 32], 16, 0, 0);
        *(ushort4*)&Bls[bn * 32 + bk4] = *(const ushort4*)&Wt2[bn * 256 + k0 + bk4];
        __syncthreads();

        short8 af[2], bfr[2];
#pragma unroll
        for (int i = 0; i < 2; ++i)
            af[i] = *(const short8*)&Als[(wave * 32 + i * 16 + fr) * 32 + fk];
#pragma unroll
        for (int j = 0; j < 2; ++j)
            bfr[j] = *(const short8*)&Bls[(j * 16 + fr) * 32 + fk];
#pragma unroll
        for (int i = 0; i < 2; ++i)
#pragma unroll
            for (int j = 0; j < 2; ++j)
                acc[i][j] = __builtin_amdgcn_mfma_f32_16x16x32_bf16(af[i], bfr[j], acc[i][j], 0, 0, 0);
        __syncthreads();
    }

    int cr = (lane >> 4) * 4, cc = lane & 15;
#pragma unroll
    for (int i = 0; i < 2; ++i) {
#pragma unroll
        for (int j = 0; j < 2; ++j) {
            int colg = j * 16 + cc;
            float bv = b2[colg];
#pragma unroll
            for (int r = 0; r < 4; ++r) {
                int rowg = rowBase + wave * 32 + i * 16 + cr + r;
                if (rowg < M) out[(size_t)rowg * 32 + colg] = acc[i][j][r] + bv;
            }
        }
    }
}

// ---------------------------------------------------------------------------
extern "C" void kernel_launch(void* const* d_in, const int* in_sizes, int n_in,
                              void* d_out, int out_size, void* d_ws, size_t ws_size,
                              hipStream_t stream) {
    const float* x   = (const float*)d_in[0];
    const int* edge  = (const int*)d_in[1];
    const float* W0  = (const float*)d_in[2];
    const float* b0  = (const float*)d_in[3];
    const float* Wn0 = (const float*)d_in[4];
    const float* bn0 = (const float*)d_in[5];
    const float* W1  = (const float*)d_in[6];
    const float* b1  = (const float*)d_in[7];
    const float* Wn1 = (const float*)d_in[8];
    const float* bn1 = (const float*)d_in[9];
    const float* W2  = (const float*)d_in[10];
    const float* b2  = (const float*)d_in[11];
    float* out = (float*)d_out;

    const int N = NN, E = NE;
    const int* row = edge;
    const int* col = edge + E;

    // Workspace layout
    char* p = (char*)d_ws;
    unsigned short* Xbf = (unsigned short*)p; p += (size_t)N * DD * 2;
    unsigned short* Abf = (unsigned short*)p; p += (size_t)N * DD * 2;
    unsigned short* Bbf = (unsigned short*)p; p += (size_t)N * DD * 2;
    unsigned short* Wt0  = (unsigned short*)p; p += 256 * 256 * 2;
    unsigned short* Wt1  = (unsigned short*)p; p += 256 * 256 * 2;
    unsigned short* WcT0 = (unsigned short*)p; p += 256 * 256 * 2;
    unsigned short* WcT1 = (unsigned short*)p; p += 256 * 256 * 2;
    unsigned short* Wt2  = (unsigned short*)p; p += 32 * 256 * 2;
    float* bc0   = (float*)p; p += 256 * 4;
    float* bc1   = (float*)p; p += 256 * 4;
    int* cnt     = (int*)p; p += (size_t)N * 4;
    int* row_ptr = (int*)p; p += (size_t)(N + 1) * 4;
    int* cursor  = (int*)p; p += (size_t)N * 4;
    float* dinv  = (float*)p; p += (size_t)N * 4;
    int* csr_col = (int*)p; p += (size_t)E * 4;
    int* bsum    = (int*)p; p += 256 * 4;
    int* bpre    = (int*)p; p += 256 * 4;

    const int nblk = (N + 255) / 256;  // 196
    const int eb = (E + 255) / 256;
    const int nTiles = (N + 127) / 128;  // 391

    // CSR build
    hipMemsetAsync(cnt, 0, (size_t)N * sizeof(int), stream);
    count_kernel<<<eb, 256, 0, stream>>>(row, cnt, E);
    block_sums<<<nblk, 256, 0, stream>>>(cnt, bsum, N);
    scan_bsums<<<1, 256, 0, stream>>>(bsum, bpre, nblk);
    fill_rowptr<<<nblk, 256, 0, stream>>>(cnt, bpre, row_ptr, cursor, dinv, N, E);
    scatter_kernel<<<eb, 256, 0, stream>>>(row, col, cursor, csr_col, E);

    // casts + weight composition: Wc = W @ Wn, bc = b @ Wn + bn
    cast_x_kernel<<<(N * DD / 4 + 255) / 256, 256, 0, stream>>>(x, Xbf, N * DD / 4);
    cast_wt3_kernel<<<dim3(256, 3), 256, 0, stream>>>(W0, W1, W2, Wt0, Wt1, Wt2);
    compose_wc<<<dim3(256, 2), 256, 0, stream>>>(W0, Wn0, W1, Wn1, WcT0, WcT1);
    compose_bc<<<dim3(1, 2), 256, 0, stream>>>(b0, Wn0, bn0, b1, Wn1, bn1, bc0, bc1);

    dim3 g(128, 4);
    // Layer 1: h -> Abf, nb -> Bbf, agg -> Abf
    dual_gemm_persist<<<g, 256, 0, stream>>>(Xbf, Wt0, WcT0, b0, bc0, Abf, Bbf, N, nTiles);
    agg_norm_relu<<<N / 4, 256, 0, stream>>>(Abf, Bbf, dinv, row_ptr, csr_col, Abf);
    // Layer 2: h -> Bbf, nb -> Xbf, agg -> Bbf
    dual_gemm_persist<<<g, 256, 0, stream>>>(Abf, Wt1, WcT1, b1, bc1, Bbf, Xbf, N, nTiles);
    agg_norm_relu<<<N / 4, 256, 0, stream>>>(Bbf, Xbf, dinv, row_ptr, csr_col, Bbf);
    // Final projection
    gemm_final_mfma<<<nTiles, 256, 0, stream>>>(Bbf, Wt2, b2, out, N);
}

// Round 6
// 427.396 us; speedup vs baseline: 1.1764x; 1.1764x over previous
//
#include <hip/hip_runtime.h>
#include <hip/hip_bf16.h>

#define NN 50000
#define NE 800000
#define DD 256
#define OO 32

typedef __attribute__((ext_vector_type(8))) short short8;
typedef __attribute__((ext_vector_type(4))) float float4v;

#define AS1 __attribute__((address_space(1)))
#define AS3 __attribute__((address_space(3)))

__device__ __forceinline__ float lo16f(unsigned int u) {
    union { unsigned int i; float f; } x; x.i = u << 16; return x.f;
}
__device__ __forceinline__ float hi16f(unsigned int u) {
    union { unsigned int i; float f; } x; x.i = u & 0xFFFF0000u; return x.f;
}
__device__ __forceinline__ unsigned short f2b(float f) {
    union { float f; unsigned int i; } x;
    x.f = f;
    unsigned int r = x.i + 0x7FFFu + ((x.i >> 16) & 1u);  // RNE
    return (unsigned short)(r >> 16);
}

// ---------------------------------------------------------------------------
// CSR build
// ---------------------------------------------------------------------------
__global__ void count_kernel(const int* __restrict__ row, int* __restrict__ cnt, int E) {
    int e = blockIdx.x * blockDim.x + threadIdx.x;
    if (e < E) atomicAdd(&cnt[row[e]], 1);
}

__global__ __launch_bounds__(256) void block_sums(const int* __restrict__ cnt,
                                                  int* __restrict__ bsum, int N) {
    __shared__ int s[256];
    int idx = blockIdx.x * 256 + threadIdx.x;
    s[threadIdx.x] = (idx < N) ? cnt[idx] : 0;
    __syncthreads();
    for (int o = 128; o > 0; o >>= 1) {
        if (threadIdx.x < o) s[threadIdx.x] += s[threadIdx.x + o];
        __syncthreads();
    }
    if (threadIdx.x == 0) bsum[blockIdx.x] = s[0];
}

__global__ __launch_bounds__(256) void scan_bsums(const int* __restrict__ bsum,
                                                  int* __restrict__ bpre, int nb) {
    __shared__ int s[256];
    int t = threadIdx.x;
    int v0 = (t < nb) ? bsum[t] : 0;
    s[t] = v0;
    __syncthreads();
    for (int o = 1; o < 256; o <<= 1) {
        int v = (t >= o) ? s[t - o] : 0;
        __syncthreads();
        s[t] += v;
        __syncthreads();
    }
    if (t < nb) bpre[t] = s[t] - v0;  // exclusive prefix
}

__global__ __launch_bounds__(256) void fill_rowptr(const int* __restrict__ cnt,
                                                   const int* __restrict__ bpre,
                                                   int* __restrict__ row_ptr,
                                                   int* __restrict__ cursor,
                                                   float* __restrict__ dinv, int N, int E) {
    __shared__ int s[256];
    int t = threadIdx.x;
    int idx = blockIdx.x * 256 + t;
    int c = (idx < N) ? cnt[idx] : 0;
    s[t] = c;
    __syncthreads();
    for (int o = 1; o < 256; o <<= 1) {
        int v = (t >= o) ? s[t - o] : 0;
        __syncthreads();
        s[t] += v;
        __syncthreads();
    }
    int excl = bpre[blockIdx.x] + s[t] - c;
    if (idx < N) {
        row_ptr[idx] = excl;
        cursor[idx] = excl;
        dinv[idx] = rsqrtf((float)(c + 1));  // +1 self-loop
    }
    if (idx == N) row_ptr[N] = E;
}

__global__ void scatter_kernel(const int* __restrict__ row, const int* __restrict__ col,
                               int* __restrict__ cursor, int* __restrict__ csr_col, int E) {
    int e = blockIdx.x * blockDim.x + threadIdx.x;
    if (e < E) {
        int p = atomicAdd(&cursor[row[e]], 1);
        csr_col[p] = col[e];
    }
}

// ---------------------------------------------------------------------------
// Casts / weight packing.
// Packed layout: Wp[kk][n][kr], kk=0..15 (kk<8 from W, kk>=8 from Wc=W@Wn),
// linear index kk*8192 + n*32 + kr. One K-step stages 16KB contiguous.
// ---------------------------------------------------------------------------
__global__ __launch_bounds__(256) void cast_x_kernel(const float* __restrict__ x,
                                                     unsigned short* __restrict__ xb, int n4) {
    int i = blockIdx.x * 256 + threadIdx.x;
    if (i < n4) {
        float4 v = ((const float4*)x)[i];
        ushort4 o;
        o.x = f2b(v.x); o.y = f2b(v.y); o.z = f2b(v.z); o.w = f2b(v.w);
        ((ushort4*)xb)[i] = o;
    }
}

__global__ __launch_bounds__(256) void cast_pack_w(const float* __restrict__ W0,
                                                   const float* __restrict__ W1,
                                                   const float* __restrict__ W2,
                                                   unsigned short* __restrict__ Wp0,
                                                   unsigned short* __restrict__ Wp1,
                                                   unsigned short* __restrict__ Wt2) {
    int n = blockIdx.x, k = threadIdx.x;
    if (blockIdx.y == 0) Wp0[(k >> 5) * 8192 + n * 32 + (k & 31)] = f2b(W0[k * 256 + n]);
    else if (blockIdx.y == 1) Wp1[(k >> 5) * 8192 + n * 32 + (k & 31)] = f2b(W1[k * 256 + n]);
    else if (n < 32) Wt2[n * 256 + k] = f2b(W2[k * 32 + n]);
}

// Wc = W @ Wn composed in fp32, written packed at kk 8..15. block=k, thread=n.
__global__ __launch_bounds__(256) void compose_wc(const float* __restrict__ W0,
                                                  const float* __restrict__ Wn0,
                                                  const float* __restrict__ W1,
                                                  const float* __restrict__ Wn1,
                                                  unsigned short* __restrict__ Wp0,
                                                  unsigned short* __restrict__ Wp1) {
    const float* W  = blockIdx.y ? W1 : W0;
    const float* Wn = blockIdx.y ? Wn1 : Wn0;
    unsigned short* T = blockIdx.y ? Wp1 : Wp0;
    __shared__ float wrow[256];
    int k = blockIdx.x, n = threadIdx.x;
    wrow[n] = W[k * 256 + n];
    __syncthreads();
    float s = 0.f;
#pragma unroll 8
    for (int m = 0; m < 256; ++m) s = fmaf(wrow[m], Wn[m * 256 + n], s);
    T[((k >> 5) + 8) * 8192 + n * 32 + (k & 31)] = f2b(s);
}

// bc[n] = sum_m b[m]*Wn[m][n] + bn[n]  (fp32)
__global__ __launch_bounds__(256) void compose_bc(const float* __restrict__ b0_,
                                                  const float* __restrict__ Wn0,
                                                  const float* __restrict__ bn0,
                                                  const float* __restrict__ b1_,
                                                  const float* __restrict__ Wn1,
                                                  const float* __restrict__ bn1,
                                                  float* __restrict__ bc0,
                                                  float* __restrict__ bc1) {
    const float* b  = blockIdx.y ? b1_ : b0_;
    const float* Wn = blockIdx.y ? Wn1 : Wn0;
    const float* bn = blockIdx.y ? bn1 : bn0;
    float* bc = blockIdx.y ? bc1 : bc0;
    int n = threadIdx.x;
    float s = bn[n];
    for (int m = 0; m < 256; ++m) s = fmaf(b[m], Wn[m * 256 + n], s);
    bc[n] = s;
}

// ---------------------------------------------------------------------------
// G = P @ A (APPNP propagation of the layer INPUT) + per-node scalar pv:
//   G_v = 0.5*dv*(dv*A_v + sum_c dc*A_c) + 0.5*A_v
//   pv_v = 0.5*dv*(dv + sum_c dc) + 0.5
// One wave per node; lane half h gathers neighbor 2j+h's row at 16B/lane.
// ---------------------------------------------------------------------------
__global__ __launch_bounds__(256) void agg_g(const unsigned short* __restrict__ A,
                                             const float* __restrict__ dinv,
                                             const int* __restrict__ row_ptr,
                                             const int* __restrict__ csr_col,
                                             unsigned short* __restrict__ G,
                                             float* __restrict__ pv) {
    int wave = threadIdx.x >> 6, lane = threadIdx.x & 63;
    int half = lane >> 5, s = lane & 31;
    int v = blockIdx.x * 4 + wave;
    float dv = dinv[v];
    const uint4* A4 = (const uint4*)A;

    float a0 = 0.f, a1 = 0.f, a2 = 0.f, a3 = 0.f;
    float a4 = 0.f, a5 = 0.f, a6 = 0.f, a7 = 0.f;
    float sdc = 0.f;

    int st = row_ptr[v], en = row_ptr[v + 1];
    for (int b0 = st; b0 < en; b0 += 64) {
        int mm = en - b0;
        if (mm > 64) mm = 64;
        int c = 0;
        float dc = 0.f;
        if (lane < mm) { c = csr_col[b0 + lane]; dc = dinv[c]; }
        sdc += dc;
        int pairs4 = (((mm + 1) >> 1) + 3) & ~3;
        for (int j = 0; j < pairs4; j += 4) {
            int ci[4];
            float di[4];
            uint4 u[4];
#pragma unroll
            for (int q = 0; q < 4; ++q) {
                int srcl = 2 * (j + q) + half;
                ci[q] = __shfl(c, srcl);
                di[q] = __shfl(dc, srcl);
            }
#pragma unroll
            for (int q = 0; q < 4; ++q) u[q] = A4[(size_t)ci[q] * 32 + s];
#pragma unroll
            for (int q = 0; q < 4; ++q) {
                a0 = fmaf(di[q], lo16f(u[q].x), a0);
                a1 = fmaf(di[q], hi16f(u[q].x), a1);
                a2 = fmaf(di[q], lo16f(u[q].y), a2);
                a3 = fmaf(di[q], hi16f(u[q].y), a3);
                a4 = fmaf(di[q], lo16f(u[q].z), a4);
                a5 = fmaf(di[q], hi16f(u[q].z), a5);
                a6 = fmaf(di[q], lo16f(u[q].w), a6);
                a7 = fmaf(di[q], hi16f(u[q].w), a7);
            }
        }
    }
    a0 += __shfl_xor(a0, 32); a1 += __shfl_xor(a1, 32);
    a2 += __shfl_xor(a2, 32); a3 += __shfl_xor(a3, 32);
    a4 += __shfl_xor(a4, 32); a5 += __shfl_xor(a5, 32);
    a6 += __shfl_xor(a6, 32); a7 += __shfl_xor(a7, 32);
#pragma unroll
    for (int o = 32; o > 0; o >>= 1) sdc += __shfl_xor(sdc, o);

    if (half == 0) {
        uint4 au = A4[(size_t)v * 32 + s];
        float av[8] = {lo16f(au.x), hi16f(au.x), lo16f(au.y), hi16f(au.y),
                       lo16f(au.z), hi16f(au.z), lo16f(au.w), hi16f(au.w)};
        float aa[8] = {a0, a1, a2, a3, a4, a5, a6, a7};
        unsigned short ov[8];
#pragma unroll
        for (int i = 0; i < 8; ++i)
            ov[i] = f2b(0.5f * dv * (dv * av[i] + aa[i]) + 0.5f * av[i]);
        *(short8*)&G[(size_t)v * 256 + s * 8] = *(short8*)ov;
    }
    if (lane == 0) pv[v] = 0.5f * dv * (dv + sdc) + 0.5f;
}

// ---------------------------------------------------------------------------
// Fused layer GEMM: Out = relu(l2norm( A@W + G@Wc + b + pv*bc )) as bf16.
// K=512 ([A|G]), block = 64 rows x 256 cols (full rows -> norm in epilogue).
// Double-buffered 16KB B tiles (packed weights) staged via global_load_lds;
// A fragments straight global->VGPR (1 load / wave / K-step). 1 barrier/K-step.
// ---------------------------------------------------------------------------
__global__ __launch_bounds__(256, 3) void gemm512_norm(const unsigned short* __restrict__ A,
                                                       const unsigned short* __restrict__ G,
                                                       const unsigned short* __restrict__ Wp,
                                                       const float* __restrict__ bias,
                                                       const float* __restrict__ biasc,
                                                       const float* __restrict__ pv,
                                                       unsigned short* __restrict__ Out,
                                                       int M) {
    __shared__ unsigned short smem[16384];  // 2 x 8KB B-buffers; epilogue: 64x256 Cls
    int tid = threadIdx.x, lane = tid & 63, wave = tid >> 6;
    int fr = lane & 15, quad = lane >> 4, fk = quad * 8;
    int rb = blockIdx.x * 64;

    int r0 = rb + wave * 16 + fr;
    if (r0 >= M) r0 = M - 1;
    const unsigned short* ap = A + (size_t)r0 * 256 + fk;
    const unsigned short* gp = G + (size_t)r0 * 256 + fk;

    float4v acc[16];
#pragma unroll
    for (int j = 0; j < 16; ++j) acc[j] = (float4v){0.f, 0.f, 0.f, 0.f};

    // stage kk=0 into buffer 0 (wave stages 4 x 1KB chunks)
#pragma unroll
    for (int i = 0; i < 4; ++i) {
        int ch = wave * 4 + i;
        __builtin_amdgcn_global_load_lds((const AS1 void*)(Wp + ch * 512 + lane * 8),
                                         (AS3 void*)&smem[ch * 512], 16, 0, 0);
    }

    for (int kk = 0; kk < 16; ++kk) {
        __syncthreads();  // stage(kk) landed; ds_reads of kk-1 done
        int cur = (kk & 1) * 8192;
        if (kk < 15) {
            int nxt = ((kk + 1) & 1) * 8192;
#pragma unroll
            for (int i = 0; i < 4; ++i) {
                int ch = wave * 4 + i;
                __builtin_amdgcn_global_load_lds(
                    (const AS1 void*)(Wp + (kk + 1) * 8192 + ch * 512 + lane * 8),
                    (AS3 void*)&smem[nxt + ch * 512], 16, 0, 0);
            }
        }
        short8 a = (kk < 8) ? *(const short8*)(ap + kk * 32)
                            : *(const short8*)(gp + (kk - 8) * 32);
#pragma unroll
        for (int j = 0; j < 16; ++j) {
            short8 b = *(const short8*)&smem[cur + (j * 16 + fr) * 32 + fk];
            acc[j] = __builtin_amdgcn_mfma_f32_16x16x32_bf16(a, b, acc[j], 0, 0, 0);
        }
    }

    // Epilogue: bias + pv*bc, row L2-norm (rows live in quad groups), relu.
    float bv[16], bcv[16];
#pragma unroll
    for (int j = 0; j < 16; ++j) {
        bv[j] = bias[j * 16 + fr];
        bcv[j] = biasc[j * 16 + fr];
    }
    float pvr[4];
#pragma unroll
    for (int r = 0; r < 4; ++r) {
        int rg = rb + wave * 16 + quad * 4 + r;
        if (rg >= M) rg = M - 1;
        pvr[r] = pv[rg];
    }
    float ss[4] = {0.f, 0.f, 0.f, 0.f};
#pragma unroll
    for (int j = 0; j < 16; ++j)
#pragma unroll
        for (int r = 0; r < 4; ++r) {
            float t = acc[j][r] + bv[j] + pvr[r] * bcv[j];
            acc[j][r] = t;
            ss[r] = fmaf(t, t, ss[r]);
        }
#pragma unroll
    for (int o = 1; o < 16; o <<= 1) {
#pragma unroll
        for (int r = 0; r < 4; ++r) ss[r] += __shfl_xor(ss[r], o);
    }
    float inv[4];
#pragma unroll
    for (int r = 0; r < 4; ++r) inv[r] = 1.0f / fmaxf(sqrtf(ss[r]), 1e-12f);

    __syncthreads();  // done with B buffers; reuse smem as Cls[64][256]
#pragma unroll
    for (int j = 0; j < 16; ++j)
#pragma unroll
        for (int r = 0; r < 4; ++r)
            smem[(wave * 16 + quad * 4 + r) * 256 + j * 16 + fr] =
                f2b(fmaxf(acc[j][r] * inv[r], 0.f));
    __syncthreads();
    // coalesced 16B stores: 2048 chunks / 256 threads
#pragma unroll
    for (int b = 0; b < 8; ++b) {
        int chunk = b * 256 + tid;
        int rw = chunk >> 5, part = chunk & 31;
        int gr = rb + rw;
        if (gr < M)
            *(short8*)&Out[(size_t)gr * 256 + part * 8] = *(const short8*)&smem[rw * 256 + part * 8];
    }
}

// ---------------------------------------------------------------------------
// Final projection (MFMA): out[M x 32](fp32) = A[M x 256](bf16) @ W2 + b2
// ---------------------------------------------------------------------------
__global__ __launch_bounds__(256) void gemm_final_mfma(const unsigned short* __restrict__ A,
                                                       const unsigned short* __restrict__ Wt2,
                                                       const float* __restrict__ b2,
                                                       float* __restrict__ out, int M) {
    __shared__ unsigned short Als[128 * 32];
    __shared__ unsigned short Bls[32 * 32];
    int tid = threadIdx.x;
    int lane = tid & 63, wave = tid >> 6;
    int rowBase = blockIdx.x * 128;

    float4v acc[2][2];
#pragma unroll
    for (int i = 0; i < 2; ++i)
#pragma unroll
        for (int j = 0; j < 2; ++j) acc[i][j] = (float4v){0.f, 0.f, 0.f, 0.f};

    int sRow = wave * 32 + (lane >> 2);
    int sK = (lane & 3) * 8;
    int fr = lane & 15, fk = (lane >> 4) * 8;
    int bn = tid >> 3, bk4 = (tid & 7) * 4;

    for (int k0 = 0; k0 < 256; k0 += 32) {
        int r0 = rowBase + sRow;       if (r0 >= M) r0 = M - 1;
        int r1 = rowBase + sRow + 16;  if (r1 >= M) r1 = M - 1;
        __builtin_amdgcn_global_load_lds((const AS1 void*)(A + (size_t)r0 * 256 + k0 + sK),
                                         (AS3 void*)&Als[(wave * 32) * 32], 16, 0, 0);
        __builtin_amdgcn_global_load_lds((const AS1 void*)(A + (size_t)r1 * 256 + k0 + sK),
                                         (AS3 void*)&Als[(wave * 32 + 16) * 32], 16, 0, 0);
        *(ushort4*)&Bls[bn * 32 + bk4] = *(const ushort4*)&Wt2[bn * 256 + k0 + bk4];
        __syncthreads();

        short8 af[2], bfr[2];
#pragma unroll
        for (int i = 0; i < 2; ++i)
            af[i] = *(const short8*)&Als[(wave * 32 + i * 16 + fr) * 32 + fk];
#pragma unroll
        for (int j = 0; j < 2; ++j)
            bfr[j] = *(const short8*)&Bls[(j * 16 + fr) * 32 + fk];
#pragma unroll
        for (int i = 0; i < 2; ++i)
#pragma unroll
            for (int j = 0; j < 2; ++j)
                acc[i][j] = __builtin_amdgcn_mfma_f32_16x16x32_bf16(af[i], bfr[j], acc[i][j], 0, 0, 0);
        __syncthreads();
    }

    int cr = (lane >> 4) * 4, cc = lane & 15;
#pragma unroll
    for (int i = 0; i < 2; ++i) {
#pragma unroll
        for (int j = 0; j < 2; ++j) {
            int colg = j * 16 + cc;
            float bv = b2[colg];
#pragma unroll
            for (int r = 0; r < 4; ++r) {
                int rowg = rowBase + wave * 32 + i * 16 + cr + r;
                if (rowg < M) out[(size_t)rowg * 32 + colg] = acc[i][j][r] + bv;
            }
        }
    }
}

// ---------------------------------------------------------------------------
extern "C" void kernel_launch(void* const* d_in, const int* in_sizes, int n_in,
                              void* d_out, int out_size, void* d_ws, size_t ws_size,
                              hipStream_t stream) {
    const float* x   = (const float*)d_in[0];
    const int* edge  = (const int*)d_in[1];
    const float* W0  = (const float*)d_in[2];
    const float* b0  = (const float*)d_in[3];
    const float* Wn0 = (const float*)d_in[4];
    const float* bn0 = (const float*)d_in[5];
    const float* W1  = (const float*)d_in[6];
    const float* b1  = (const float*)d_in[7];
    const float* Wn1 = (const float*)d_in[8];
    const float* bn1 = (const float*)d_in[9];
    const float* W2  = (const float*)d_in[10];
    const float* b2  = (const float*)d_in[11];
    float* out = (float*)d_out;

    const int N = NN, E = NE;
    const int* row = edge;
    const int* col = edge + E;

    // Workspace layout
    char* p = (char*)d_ws;
    unsigned short* Xbf = (unsigned short*)p; p += (size_t)N * DD * 2;
    unsigned short* Gbf = (unsigned short*)p; p += (size_t)N * DD * 2;
    unsigned short* Abf = (unsigned short*)p; p += (size_t)N * DD * 2;
    unsigned short* Wp0 = (unsigned short*)p; p += 16 * 8192 * 2;  // packed [W0|Wc0]
    unsigned short* Wp1 = (unsigned short*)p; p += 16 * 8192 * 2;  // packed [W1|Wc1]
    unsigned short* Wt2 = (unsigned short*)p; p += 32 * 256 * 2;
    float* bc0   = (float*)p; p += 256 * 4;
    float* bc1   = (float*)p; p += 256 * 4;
    float* pv    = (float*)p; p += (size_t)N * 4;
    int* cnt     = (int*)p; p += (size_t)N * 4;
    int* row_ptr = (int*)p; p += (size_t)(N + 1) * 4;
    int* cursor  = (int*)p; p += (size_t)N * 4;
    float* dinv  = (float*)p; p += (size_t)N * 4;
    int* csr_col = (int*)p; p += (size_t)E * 4;
    int* bsum    = (int*)p; p += 256 * 4;
    int* bpre    = (int*)p; p += 256 * 4;

    const int nblk = (N + 255) / 256;  // 196
    const int eb = (E + 255) / 256;

    // CSR build
    hipMemsetAsync(cnt, 0, (size_t)N * sizeof(int), stream);
    count_kernel<<<eb, 256, 0, stream>>>(row, cnt, E);
    block_sums<<<nblk, 256, 0, stream>>>(cnt, bsum, N);
    scan_bsums<<<1, 256, 0, stream>>>(bsum, bpre, nblk);
    fill_rowptr<<<nblk, 256, 0, stream>>>(cnt, bpre, row_ptr, cursor, dinv, N, E);
    scatter_kernel<<<eb, 256, 0, stream>>>(row, col, cursor, csr_col, E);

    // casts + packed weights + composed bias
    cast_x_kernel<<<(N * DD / 4 + 255) / 256, 256, 0, stream>>>(x, Xbf, N * DD / 4);
    cast_pack_w<<<dim3(256, 3), 256, 0, stream>>>(W0, W1, W2, Wp0, Wp1, Wt2);
    compose_wc<<<dim3(256, 2), 256, 0, stream>>>(W0, Wn0, W1, Wn1, Wp0, Wp1);
    compose_bc<<<dim3(1, 2), 256, 0, stream>>>(b0, Wn0, bn0, b1, Wn1, bn1, bc0, bc1);

    const int gTiles = (N + 63) / 64;  // 782
    // Layer 1: G1 = P@X ; A2 = relu(l2norm(X@W0 + G1@Wc0 + b0 + pv*bc0))
    agg_g<<<N / 4, 256, 0, stream>>>(Xbf, dinv, row_ptr, csr_col, Gbf, pv);
    gemm512_norm<<<gTiles, 256, 0, stream>>>(Xbf, Gbf, Wp0, b0, bc0, pv, Abf, N);
    // Layer 2: G2 = P@A2 ; A3 = relu(l2norm(A2@W1 + G2@Wc1 + b1 + pv*bc1)) -> Xbf
    agg_g<<<N / 4, 256, 0, stream>>>(Abf, dinv, row_ptr, csr_col, Gbf, pv);
    gemm512_norm<<<gTiles, 256, 0, stream>>>(Abf, Gbf, Wp1, b1, bc1, pv, Xbf, N);
    // Final projection
    gemm_final_mfma<<<(N + 127) / 128, 256, 0, stream>>>(Xbf, Wt2, b2, out, N);
}

// Round 7
// 395.232 us; speedup vs baseline: 1.2721x; 1.0814x over previous
//
#include <hip/hip_runtime.h>
#include <hip/hip_bf16.h>

#define NN 50000
#define NE 800000
#define DD 256
#define OO 32

typedef __attribute__((ext_vector_type(8))) short short8;
typedef __attribute__((ext_vector_type(4))) float float4v;

#define AS1 __attribute__((address_space(1)))
#define AS3 __attribute__((address_space(3)))

__device__ __forceinline__ float lo16f(unsigned int u) {
    union { unsigned int i; float f; } x; x.i = u << 16; return x.f;
}
__device__ __forceinline__ float hi16f(unsigned int u) {
    union { unsigned int i; float f; } x; x.i = u & 0xFFFF0000u; return x.f;
}
__device__ __forceinline__ unsigned short f2b(float f) {
    union { float f; unsigned int i; } x;
    x.f = f;
    unsigned int r = x.i + 0x7FFFu + ((x.i >> 16) & 1u);  // RNE
    return (unsigned short)(r >> 16);
}

// ---------------------------------------------------------------------------
// CSR build
// ---------------------------------------------------------------------------
__global__ void count_kernel(const int* __restrict__ row, int* __restrict__ cnt, int E) {
    int e = blockIdx.x * blockDim.x + threadIdx.x;
    if (e < E) atomicAdd(&cnt[row[e]], 1);
}

__global__ __launch_bounds__(256) void block_sums(const int* __restrict__ cnt,
                                                  int* __restrict__ bsum, int N) {
    __shared__ int s[256];
    int idx = blockIdx.x * 256 + threadIdx.x;
    s[threadIdx.x] = (idx < N) ? cnt[idx] : 0;
    __syncthreads();
    for (int o = 128; o > 0; o >>= 1) {
        if (threadIdx.x < o) s[threadIdx.x] += s[threadIdx.x + o];
        __syncthreads();
    }
    if (threadIdx.x == 0) bsum[blockIdx.x] = s[0];
}

__global__ __launch_bounds__(256) void scan_bsums(const int* __restrict__ bsum,
                                                  int* __restrict__ bpre, int nb) {
    __shared__ int s[256];
    int t = threadIdx.x;
    int v0 = (t < nb) ? bsum[t] : 0;
    s[t] = v0;
    __syncthreads();
    for (int o = 1; o < 256; o <<= 1) {
        int v = (t >= o) ? s[t - o] : 0;
        __syncthreads();
        s[t] += v;
        __syncthreads();
    }
    if (t < nb) bpre[t] = s[t] - v0;  // exclusive prefix
}

__global__ __launch_bounds__(256) void fill_rowptr(const int* __restrict__ cnt,
                                                   const int* __restrict__ bpre,
                                                   int* __restrict__ row_ptr,
                                                   int* __restrict__ cursor,
                                                   float* __restrict__ dinv, int N, int E) {
    __shared__ int s[256];
    int t = threadIdx.x;
    int idx = blockIdx.x * 256 + t;
    int c = (idx < N) ? cnt[idx] : 0;
    s[t] = c;
    __syncthreads();
    for (int o = 1; o < 256; o <<= 1) {
        int v = (t >= o) ? s[t - o] : 0;
        __syncthreads();
        s[t] += v;
        __syncthreads();
    }
    int excl = bpre[blockIdx.x] + s[t] - c;
    if (idx < N) {
        row_ptr[idx] = excl;
        cursor[idx] = excl;
        dinv[idx] = rsqrtf((float)(c + 1));  // +1 self-loop
    }
    if (idx == N) row_ptr[N] = E;
}

__global__ void scatter_kernel(const int* __restrict__ row, const int* __restrict__ col,
                               int* __restrict__ cursor, int* __restrict__ csr_col, int E) {
    int e = blockIdx.x * blockDim.x + threadIdx.x;
    if (e < E) {
        int p = atomicAdd(&cursor[row[e]], 1);
        csr_col[p] = col[e];
    }
}

// ---------------------------------------------------------------------------
// Casts / weight packing.
// Fragment-order packed layout (conflict-free LDS): for element (k, n):
//   kk=k>>5, quad=(k&31)>>3, k8=k&7, j=n>>4, fr=n&15
//   idx = kk*8192 + j*512 + (quad*16+fr)*8 + k8
// A K-step (kk) is 16KB contiguous; a wave's ds_read_b128 for fragment j is
// base + j*512 + lane*8 — wave-linear, zero bank conflicts.
// ---------------------------------------------------------------------------
__global__ __launch_bounds__(256) void cast_x_kernel(const float* __restrict__ x,
                                                     unsigned short* __restrict__ xb, int n4) {
    int i = blockIdx.x * 256 + threadIdx.x;
    if (i < n4) {
        float4 v = ((const float4*)x)[i];
        ushort4 o;
        o.x = f2b(v.x); o.y = f2b(v.y); o.z = f2b(v.z); o.w = f2b(v.w);
        ((ushort4*)xb)[i] = o;
    }
}

__device__ __forceinline__ int pack_idx(int k, int n) {
    return (k >> 5) * 8192 + (n >> 4) * 512 + (((k & 31) >> 3) * 16 + (n & 15)) * 8 + (k & 7);
}

__global__ __launch_bounds__(256) void cast_pack_w(const float* __restrict__ W0,
                                                   const float* __restrict__ W1,
                                                   const float* __restrict__ W2,
                                                   unsigned short* __restrict__ Wp0,
                                                   unsigned short* __restrict__ Wp1,
                                                   unsigned short* __restrict__ Wt2) {
    int n = blockIdx.x, k = threadIdx.x;
    if (blockIdx.y == 0) Wp0[pack_idx(k, n)] = f2b(W0[k * 256 + n]);
    else if (blockIdx.y == 1) Wp1[pack_idx(k, n)] = f2b(W1[k * 256 + n]);
    else if (n < 32) Wt2[n * 256 + k] = f2b(W2[k * 32 + n]);
}

// Wc = W @ Wn composed in fp32, packed at kk 8..15. block=k, thread=n.
__global__ __launch_bounds__(256) void compose_wc(const float* __restrict__ W0,
                                                  const float* __restrict__ Wn0,
                                                  const float* __restrict__ W1,
                                                  const float* __restrict__ Wn1,
                                                  unsigned short* __restrict__ Wp0,
                                                  unsigned short* __restrict__ Wp1) {
    const float* W  = blockIdx.y ? W1 : W0;
    const float* Wn = blockIdx.y ? Wn1 : Wn0;
    unsigned short* T = blockIdx.y ? Wp1 : Wp0;
    __shared__ float wrow[256];
    int k = blockIdx.x, n = threadIdx.x;
    wrow[n] = W[k * 256 + n];
    __syncthreads();
    float s = 0.f;
#pragma unroll 8
    for (int m = 0; m < 256; ++m) s = fmaf(wrow[m], Wn[m * 256 + n], s);
    T[pack_idx(k + 256, n)] = f2b(s);
}

// bc[n] = sum_m b[m]*Wn[m][n] + bn[n]  (fp32)
__global__ __launch_bounds__(256) void compose_bc(const float* __restrict__ b0_,
                                                  const float* __restrict__ Wn0,
                                                  const float* __restrict__ bn0,
                                                  const float* __restrict__ b1_,
                                                  const float* __restrict__ Wn1,
                                                  const float* __restrict__ bn1,
                                                  float* __restrict__ bc0,
                                                  float* __restrict__ bc1) {
    const float* b  = blockIdx.y ? b1_ : b0_;
    const float* Wn = blockIdx.y ? Wn1 : Wn0;
    const float* bn = blockIdx.y ? bn1 : bn0;
    float* bc = blockIdx.y ? bc1 : bc0;
    int n = threadIdx.x;
    float s = bn[n];
    for (int m = 0; m < 256; ++m) s = fmaf(b[m], Wn[m * 256 + n], s);
    bc[n] = s;
}

// ---------------------------------------------------------------------------
// G = P @ A (APPNP propagation of the layer INPUT) + per-node scalar pv.
// ---------------------------------------------------------------------------
__global__ __launch_bounds__(256) void agg_g(const unsigned short* __restrict__ A,
                                             const float* __restrict__ dinv,
                                             const int* __restrict__ row_ptr,
                                             const int* __restrict__ csr_col,
                                             unsigned short* __restrict__ G,
                                             float* __restrict__ pv) {
    int wave = threadIdx.x >> 6, lane = threadIdx.x & 63;
    int half = lane >> 5, s = lane & 31;
    int v = blockIdx.x * 4 + wave;
    float dv = dinv[v];
    const uint4* A4 = (const uint4*)A;

    float a0 = 0.f, a1 = 0.f, a2 = 0.f, a3 = 0.f;
    float a4 = 0.f, a5 = 0.f, a6 = 0.f, a7 = 0.f;
    float sdc = 0.f;

    int st = row_ptr[v], en = row_ptr[v + 1];
    for (int b0 = st; b0 < en; b0 += 64) {
        int mm = en - b0;
        if (mm > 64) mm = 64;
        int c = 0;
        float dc = 0.f;
        if (lane < mm) { c = csr_col[b0 + lane]; dc = dinv[c]; }
        sdc += dc;
        int pairs4 = (((mm + 1) >> 1) + 3) & ~3;
        for (int j = 0; j < pairs4; j += 4) {
            int ci[4];
            float di[4];
            uint4 u[4];
#pragma unroll
            for (int q = 0; q < 4; ++q) {
                int srcl = 2 * (j + q) + half;
                ci[q] = __shfl(c, srcl);
                di[q] = __shfl(dc, srcl);
            }
#pragma unroll
            for (int q = 0; q < 4; ++q) u[q] = A4[(size_t)ci[q] * 32 + s];
#pragma unroll
            for (int q = 0; q < 4; ++q) {
                a0 = fmaf(di[q], lo16f(u[q].x), a0);
                a1 = fmaf(di[q], hi16f(u[q].x), a1);
                a2 = fmaf(di[q], lo16f(u[q].y), a2);
                a3 = fmaf(di[q], hi16f(u[q].y), a3);
                a4 = fmaf(di[q], lo16f(u[q].z), a4);
                a5 = fmaf(di[q], hi16f(u[q].z), a5);
                a6 = fmaf(di[q], lo16f(u[q].w), a6);
                a7 = fmaf(di[q], hi16f(u[q].w), a7);
            }
        }
    }
    a0 += __shfl_xor(a0, 32); a1 += __shfl_xor(a1, 32);
    a2 += __shfl_xor(a2, 32); a3 += __shfl_xor(a3, 32);
    a4 += __shfl_xor(a4, 32); a5 += __shfl_xor(a5, 32);
    a6 += __shfl_xor(a6, 32); a7 += __shfl_xor(a7, 32);
#pragma unroll
    for (int o = 32; o > 0; o >>= 1) sdc += __shfl_xor(sdc, o);

    if (half == 0) {
        uint4 au = A4[(size_t)v * 32 + s];
        float av[8] = {lo16f(au.x), hi16f(au.x), lo16f(au.y), hi16f(au.y),
                       lo16f(au.z), hi16f(au.z), lo16f(au.w), hi16f(au.w)};
        float aa[8] = {a0, a1, a2, a3, a4, a5, a6, a7};
        unsigned short ov[8];
#pragma unroll
        for (int i = 0; i < 8; ++i)
            ov[i] = f2b(0.5f * dv * (dv * av[i] + aa[i]) + 0.5f * av[i]);
        *(short8*)&G[(size_t)v * 256 + s * 8] = *(short8*)ov;
    }
    if (lane == 0) pv[v] = 0.5f * dv * (dv + sdc) + 0.5f;
}

// ---------------------------------------------------------------------------
// Fused layer GEMM: Out = relu(l2norm( A@W + G@Wc + b + pv*bc )) as bf16.
// K=512 ([A|G]), block = 128 rows x 256 cols, wave = 32 rows (2 A-frags).
// B staged via global_load_lds in fragment order (conflict-free ds_read_b128
// at base + j*512 + lane*8). A frags global->VGPR, prefetched 1 K-step ahead.
// Epilogue: 2 rounds of 64-row LDS-staged coalesced stores.
// ---------------------------------------------------------------------------
__global__ __launch_bounds__(256, 2) void gemm512_norm(const unsigned short* __restrict__ A,
                                                       const unsigned short* __restrict__ G,
                                                       const unsigned short* __restrict__ Wp,
                                                       const float* __restrict__ bias,
                                                       const float* __restrict__ biasc,
                                                       const float* __restrict__ pv,
                                                       unsigned short* __restrict__ Out,
                                                       int M) {
    __shared__ unsigned short smem[16384];  // 2 x 16KB B dbuf; epilogue 64x256 Cls
    int tid = threadIdx.x, lane = tid & 63, wave = tid >> 6;
    int fr = lane & 15, quad = lane >> 4, fk = quad * 8;
    int rb = blockIdx.x * 128;

    int r0 = rb + wave * 32 + fr;      if (r0 >= M) r0 = M - 1;
    int r1 = rb + wave * 32 + 16 + fr; if (r1 >= M) r1 = M - 1;
    const unsigned short* ap0 = A + (size_t)r0 * 256 + fk;
    const unsigned short* ap1 = A + (size_t)r1 * 256 + fk;
    const unsigned short* gp0 = G + (size_t)r0 * 256 + fk;
    const unsigned short* gp1 = G + (size_t)r1 * 256 + fk;

    float4v acc[2][16];
#pragma unroll
    for (int i = 0; i < 2; ++i)
#pragma unroll
        for (int j = 0; j < 16; ++j) acc[i][j] = (float4v){0.f, 0.f, 0.f, 0.f};

    // stage kk=0 into buffer 0 (each wave stages 4 x 1KB chunks)
#pragma unroll
    for (int i = 0; i < 4; ++i) {
        int ch = wave * 4 + i;
        __builtin_amdgcn_global_load_lds((const AS1 void*)(Wp + ch * 512 + lane * 8),
                                         (AS3 void*)&smem[ch * 512], 16, 0, 0);
    }
    short8 a0c = *(const short8*)ap0;
    short8 a1c = *(const short8*)ap1;

    for (int kk = 0; kk < 16; ++kk) {
        __syncthreads();  // stage(kk) landed; reads of kk-1 done
        int cur = (kk & 1) * 8192;
        if (kk < 15) {
            int nxt = ((kk + 1) & 1) * 8192;
#pragma unroll
            for (int i = 0; i < 4; ++i) {
                int ch = wave * 4 + i;
                __builtin_amdgcn_global_load_lds(
                    (const AS1 void*)(Wp + (kk + 1) * 8192 + ch * 512 + lane * 8),
                    (AS3 void*)&smem[nxt + ch * 512], 16, 0, 0);
            }
        }
        // prefetch next A fragments
        short8 a0n, a1n;
        if (kk < 15) {
            int kn = kk + 1;
            a0n = (kn < 8) ? *(const short8*)(ap0 + kn * 32) : *(const short8*)(gp0 + (kn - 8) * 32);
            a1n = (kn < 8) ? *(const short8*)(ap1 + kn * 32) : *(const short8*)(gp1 + (kn - 8) * 32);
        }
#pragma unroll
        for (int j = 0; j < 16; ++j) {
            short8 b = *(const short8*)&smem[cur + j * 512 + lane * 8];
            acc[0][j] = __builtin_amdgcn_mfma_f32_16x16x32_bf16(a0c, b, acc[0][j], 0, 0, 0);
            acc[1][j] = __builtin_amdgcn_mfma_f32_16x16x32_bf16(a1c, b, acc[1][j], 0, 0, 0);
        }
        a0c = a0n;
        a1c = a1n;
    }

    // Epilogue: bias + pv*bc, row L2-norm, relu.
    float bv[16], bcv[16];
#pragma unroll
    for (int j = 0; j < 16; ++j) {
        bv[j] = bias[j * 16 + fr];
        bcv[j] = biasc[j * 16 + fr];
    }
    float pvr[2][4];
#pragma unroll
    for (int i = 0; i < 2; ++i)
#pragma unroll
        for (int r = 0; r < 4; ++r) {
            int rg = rb + wave * 32 + i * 16 + quad * 4 + r;
            if (rg >= M) rg = M - 1;
            pvr[i][r] = pv[rg];
        }
    float ss[2][4] = {{0.f, 0.f, 0.f, 0.f}, {0.f, 0.f, 0.f, 0.f}};
#pragma unroll
    for (int i = 0; i < 2; ++i)
#pragma unroll
        for (int j = 0; j < 16; ++j)
#pragma unroll
            for (int r = 0; r < 4; ++r) {
                float t = acc[i][j][r] + bv[j] + pvr[i][r] * bcv[j];
                acc[i][j][r] = t;
                ss[i][r] = fmaf(t, t, ss[i][r]);
            }
#pragma unroll
    for (int o = 1; o < 16; o <<= 1)
#pragma unroll
        for (int i = 0; i < 2; ++i)
#pragma unroll
            for (int r = 0; r < 4; ++r) ss[i][r] += __shfl_xor(ss[i][r], o);
    float inv[2][4];
#pragma unroll
    for (int i = 0; i < 2; ++i)
#pragma unroll
        for (int r = 0; r < 4; ++r) inv[i][r] = 1.0f / fmaxf(sqrtf(ss[i][r]), 1e-12f);

    // 2 rounds of 64 rows: waves (2rd, 2rd+1) stage, all store coalesced.
#pragma unroll
    for (int rd = 0; rd < 2; ++rd) {
        __syncthreads();
        if ((wave >> 1) == rd) {
#pragma unroll
            for (int i = 0; i < 2; ++i)
#pragma unroll
                for (int j = 0; j < 16; ++j)
#pragma unroll
                    for (int r = 0; r < 4; ++r)
                        smem[((wave & 1) * 32 + i * 16 + quad * 4 + r) * 256 + j * 16 + fr] =
                            f2b(fmaxf(acc[i][j][r] * inv[i][r], 0.f));
        }
        __syncthreads();
#pragma unroll
        for (int b = 0; b < 8; ++b) {
            int chunk = b * 256 + tid;       // 2048 chunks of 8 ushorts
            int rw = chunk >> 5, part = chunk & 31;
            int gr = rb + rd * 64 + rw;
            if (gr < M)
                *(short8*)&Out[(size_t)gr * 256 + part * 8] =
                    *(const short8*)&smem[rw * 256 + part * 8];
        }
    }
}

// ---------------------------------------------------------------------------
// Final projection (MFMA): out[M x 32](fp32) = A[M x 256](bf16) @ W2 + b2
// ---------------------------------------------------------------------------
__global__ __launch_bounds__(256) void gemm_final_mfma(const unsigned short* __restrict__ A,
                                                       const unsigned short* __restrict__ Wt2,
                                                       const float* __restrict__ b2,
                                                       float* __restrict__ out, int M) {
    __shared__ unsigned short Als[128 * 32];
    __shared__ unsigned short Bls[32 * 32];
    int tid = threadIdx.x;
    int lane = tid & 63, wave = tid >> 6;
    int rowBase = blockIdx.x * 128;

    float4v acc[2][2];
#pragma unroll
    for (int i = 0; i < 2; ++i)
#pragma unroll
        for (int j = 0; j < 2; ++j) acc[i][j] = (float4v){0.f, 0.f, 0.f, 0.f};

    int sRow = wave * 32 + (lane >> 2);
    int sK = (lane & 3) * 8;
    int fr = lane & 15, fk = (lane >> 4) * 8;
    int bn = tid >> 3, bk4 = (tid & 7) * 4;

    for (int k0 = 0; k0 < 256; k0 += 32) {
        int r0 = rowBase + sRow;       if (r0 >= M) r0 = M - 1;
        int r1 = rowBase + sRow + 16;  if (r1 >= M) r1 = M - 1;
        __builtin_amdgcn_global_load_lds((const AS1 void*)(A + (size_t)r0 * 256 + k0 + sK),
                                         (AS3 void*)&Als[(wave * 32) * 32], 16, 0, 0);
        __builtin_amdgcn_global_load_lds((const AS1 void*)(A + (size_t)r1 * 256 + k0 + sK),
                                         (AS3 void*)&Als[(wave * 32 + 16) * 32], 16, 0, 0);
        *(ushort4*)&Bls[bn * 32 + bk4] = *(const ushort4*)&Wt2[bn * 256 + k0 + bk4];
        __syncthreads();

        short8 af[2], bfr[2];
#pragma unroll
        for (int i = 0; i < 2; ++i)
            af[i] = *(const short8*)&Als[(wave * 32 + i * 16 + fr) * 32 + fk];
#pragma unroll
        for (int j = 0; j < 2; ++j)
            bfr[j] = *(const short8*)&Bls[(j * 16 + fr) * 32 + fk];
#pragma unroll
        for (int i = 0; i < 2; ++i)
#pragma unroll
            for (int j = 0; j < 2; ++j)
                acc[i][j] = __builtin_amdgcn_mfma_f32_16x16x32_bf16(af[i], bfr[j], acc[i][j], 0, 0, 0);
        __syncthreads();
    }

    int cr = (lane >> 4) * 4, cc = lane & 15;
#pragma unroll
    for (int i = 0; i < 2; ++i) {
#pragma unroll
        for (int j = 0; j < 2; ++j) {
            int colg = j * 16 + cc;
            float bv = b2[colg];
#pragma unroll
            for (int r = 0; r < 4; ++r) {
                int rowg = rowBase + wave * 32 + i * 16 + cr + r;
                if (rowg < M) out[(size_t)rowg * 32 + colg] = acc[i][j][r] + bv;
            }
        }
    }
}

// ---------------------------------------------------------------------------
extern "C" void kernel_launch(void* const* d_in, const int* in_sizes, int n_in,
                              void* d_out, int out_size, void* d_ws, size_t ws_size,
                              hipStream_t stream) {
    const float* x   = (const float*)d_in[0];
    const int* edge  = (const int*)d_in[1];
    const float* W0  = (const float*)d_in[2];
    const float* b0  = (const float*)d_in[3];
    const float* Wn0 = (const float*)d_in[4];
    const float* bn0 = (const float*)d_in[5];
    const float* W1  = (const float*)d_in[6];
    const float* b1  = (const float*)d_in[7];
    const float* Wn1 = (const float*)d_in[8];
    const float* bn1 = (const float*)d_in[9];
    const float* W2  = (const float*)d_in[10];
    const float* b2  = (const float*)d_in[11];
    float* out = (float*)d_out;

    const int N = NN, E = NE;
    const int* row = edge;
    const int* col = edge + E;

    // Workspace layout
    char* p = (char*)d_ws;
    unsigned short* Xbf = (unsigned short*)p; p += (size_t)N * DD * 2;
    unsigned short* Gbf = (unsigned short*)p; p += (size_t)N * DD * 2;
    unsigned short* Abf = (unsigned short*)p; p += (size_t)N * DD * 2;
    unsigned short* Wp0 = (unsigned short*)p; p += 16 * 8192 * 2;  // packed [W0|Wc0]
    unsigned short* Wp1 = (unsigned short*)p; p += 16 * 8192 * 2;  // packed [W1|Wc1]
    unsigned short* Wt2 = (unsigned short*)p; p += 32 * 256 * 2;
    float* bc0   = (float*)p; p += 256 * 4;
    float* bc1   = (float*)p; p += 256 * 4;
    float* pv    = (float*)p; p += (size_t)N * 4;
    int* cnt     = (int*)p; p += (size_t)N * 4;
    int* row_ptr = (int*)p; p += (size_t)(N + 1) * 4;
    int* cursor  = (int*)p; p += (size_t)N * 4;
    float* dinv  = (float*)p; p += (size_t)N * 4;
    int* csr_col = (int*)p; p += (size_t)E * 4;
    int* bsum    = (int*)p; p += 256 * 4;
    int* bpre    = (int*)p; p += 256 * 4;

    const int nblk = (N + 255) / 256;  // 196
    const int eb = (E + 255) / 256;

    // CSR build
    hipMemsetAsync(cnt, 0, (size_t)N * sizeof(int), stream);
    count_kernel<<<eb, 256, 0, stream>>>(row, cnt, E);
    block_sums<<<nblk, 256, 0, stream>>>(cnt, bsum, N);
    scan_bsums<<<1, 256, 0, stream>>>(bsum, bpre, nblk);
    fill_rowptr<<<nblk, 256, 0, stream>>>(cnt, bpre, row_ptr, cursor, dinv, N, E);
    scatter_kernel<<<eb, 256, 0, stream>>>(row, col, cursor, csr_col, E);

    // casts + packed weights + composed bias
    cast_x_kernel<<<(N * DD / 4 + 255) / 256, 256, 0, stream>>>(x, Xbf, N * DD / 4);
    cast_pack_w<<<dim3(256, 3), 256, 0, stream>>>(W0, W1, W2, Wp0, Wp1, Wt2);
    compose_wc<<<dim3(256, 2), 256, 0, stream>>>(W0, Wn0, W1, Wn1, Wp0, Wp1);
    compose_bc<<<dim3(1, 2), 256, 0, stream>>>(b0, Wn0, bn0, b1, Wn1, bn1, bc0, bc1);

    const int gTiles = (N + 127) / 128;  // 391
    // Layer 1: G1 = P@X ; A2 = relu(l2norm(X@W0 + G1@Wc0 + b0 + pv*bc0))
    agg_g<<<N / 4, 256, 0, stream>>>(Xbf, dinv, row_ptr, csr_col, Gbf, pv);
    gemm512_norm<<<gTiles, 256, 0, stream>>>(Xbf, Gbf, Wp0, b0, bc0, pv, Abf, N);
    // Layer 2: G2 = P@A2 ; A3 = relu(l2norm(A2@W1 + G2@Wc1 + b1 + pv*bc1)) -> Xbf
    agg_g<<<N / 4, 256, 0, stream>>>(Abf, dinv, row_ptr, csr_col, Gbf, pv);
    gemm512_norm<<<gTiles, 256, 0, stream>>>(Abf, Gbf, Wp1, b1, bc1, pv, Xbf, N);
    // Final projection
    gemm_final_mfma<<<(N + 127) / 128, 256, 0, stream>>>(Xbf, Wt2, b2, out, N);
}